// Round 9
// baseline (637.637 us; speedup 1.0000x reference)
//
#include <hip/hip_runtime.h>

#define B_  2
#define S_  2048
#define D_  512
#define H_  8
#define E_  512
#define HE_ 4096

typedef _Float16 half8_t  __attribute__((ext_vector_type(8)));
typedef _Float16 half4_t  __attribute__((ext_vector_type(4)));
typedef float    floatx4  __attribute__((ext_vector_type(4)));
typedef __attribute__((address_space(1))) const unsigned int* gas_ptr;
typedef __attribute__((address_space(3))) unsigned int*       las_ptr;

// ---------------- fused cast fp32 -> fp16 for q,k,v ----------------
__global__ __launch_bounds__(256) void cast3_f16_kernel(
    const float* __restrict__ s0, const float* __restrict__ s1, const float* __restrict__ s2,
    _Float16* __restrict__ d0, _Float16* __restrict__ d1, _Float16* __restrict__ d2, int n4) {
    int i = blockIdx.x * 256 + threadIdx.x;
    if (i >= n4) return;
    const float* s = (blockIdx.y == 0) ? s0 : (blockIdx.y == 1) ? s1 : s2;
    _Float16*    d = (blockIdx.y == 0) ? d0 : (blockIdx.y == 1) ? d1 : d2;
    float4 v = ((const float4*)s)[i];
    half4_t h = { (_Float16)v.x, (_Float16)v.y, (_Float16)v.z, (_Float16)v.w };
    ((half4_t*)d)[i] = h;
}

// ------------- pack fp32 src[R][C] -> fp16 B' fragment layout -----------------
// B'(n = C-dim, k = R-dim): tile (ntile=n/16, ktile=k/32) of 512 elems; element
// (n,k) at offset ((k%32)/8*16 + n%16)*8 + k%8  == lane-major MFMA B-fragment.
__global__ __launch_bounds__(256) void pack3_kernel(
    const float* __restrict__ p0, const float* __restrict__ p1, const float* __restrict__ p2,
    _Float16* __restrict__ q0, _Float16* __restrict__ q1, _Float16* __restrict__ q2,
    int R, int C) {
    int which = blockIdx.z >> 3, hh = blockIdx.z & 7;
    const float* src = ((which == 0) ? p0 : (which == 1) ? p1 : p2) + (long long)hh * R * C;
    _Float16*    dst = ((which == 0) ? q0 : (which == 1) ? q1 : q2) + (long long)hh * R * C;
    int nt = blockIdx.x;
    int kt = blockIdx.y * 4 + (threadIdx.x >> 6);
    int lane = threadIdx.x & 63, quad = lane >> 4, l16 = lane & 15;
    int n = nt * 16 + l16;
    half8_t h;
#pragma unroll
    for (int e = 0; e < 8; e++)
        h[e] = (_Float16)src[(long long)(kt * 32 + quad * 8 + e) * C + n];
    *(half8_t*)(dst + ((long long)(nt * (R >> 5) + kt)) * 512 + lane * 8) = h;
}

__global__ __launch_bounds__(256) void pack1_kernel(const float* __restrict__ src,
                                                    _Float16* __restrict__ dst,
                                                    int R, int C) {
    int nt = blockIdx.x;
    int kt = blockIdx.y * 4 + (threadIdx.x >> 6);
    int lane = threadIdx.x & 63, quad = lane >> 4, l16 = lane & 15;
    int n = nt * 16 + l16;
    half8_t h;
#pragma unroll
    for (int e = 0; e < 8; e++)
        h[e] = (_Float16)src[(long long)(kt * 32 + quad * 8 + e) * C + n];
    *(half8_t*)(dst + ((long long)(nt * (R >> 5) + kt)) * 512 + lane * 8) = h;
}

// ------------- GEMM: A via LDS (BK=64 panels, XOR-swizzled), B' direct-to-VGPR ----------
// C[M,N] = A[M,K]*B'[N,K]^T (+bias). 128x128 tile, 4 waves 2x2, wave 64x64.
// B fragments: one coalesced 16B/lane load per tile from packed layout (no LDS).
// A staging col-swizzle: global cg (lane&3)^((lane>>3)&3) lands at LDS slot lane&3,
// so af ds_read_b128 spreads each 32-lane half over all 32 banks (2 lanes/bank, free).
// out_mode: 0 f16 flat, 1 f32 flat, 2 f16 packed(n=row), 3 f16 packed(n=col).
__global__ __launch_bounds__(256) void gemm_asb_kernel(
    const _Float16* __restrict__ A, const _Float16* __restrict__ Bsw,
    const float* __restrict__ bias, void* __restrict__ C, int out_mode,
    int K, int lda, int ldb32,
    long long a_b, long long a_h, long long b_b, long long b_h,
    long long c_b, long long c_h, int c_rs, int c_cs, int c_ld,
    int divh, int bias_h)
{
    int z  = blockIdx.z;
    int bb = z / divh, hh = z % divh;
    A   += bb * a_b + hh * a_h;
    Bsw += bb * b_b + hh * b_h;
    long long coff = bb * c_b + hh * c_h;

    int m0 = blockIdx.y * 128;
    int n0 = blockIdx.x * 128;

    __shared__ __align__(16) _Float16 As[2][128][32];   // 16 KB (A only)

    int tid  = threadIdx.x;
    int wave = tid >> 6, lane = tid & 63;
    int quad = lane >> 4, l16 = lane & 15;
    int wy = (wave >> 1) * 64, wx = (wave & 1) * 64;

    int pw = wave & 1;              // k-panel
    int rw = (wave >> 1) * 64;      // row base
    int sr = lane >> 2;
    int scg = ((lane & 3) ^ ((lane >> 3) & 3)) * 8;    // swizzled global col
    _Float16* lA0 = &As[pw][rw][0];
    int cra = (quad ^ ((l16 >> 1) & 3)) * 8;           // swizzle undo for af read

    int nblk = (n0 + wx) >> 4;

    floatx4 acc[4][4] = {};

    for (int k0 = 0; k0 < K; k0 += 64) {
        if (k0) __syncthreads();
        const _Float16* gA = A + (long long)(m0 + rw + sr) * lda + k0 + pw * 32 + scg;
#pragma unroll
        for (int j = 0; j < 4; j++)
            __builtin_amdgcn_global_load_lds((gas_ptr)(gA + (long long)(j * 16) * lda),
                                             (las_ptr)(lA0 + j * 512), 16, 0, 0);
        half8_t bf[2][4];
        int kb = k0 >> 5;
#pragma unroll
        for (int p = 0; p < 2; p++)
#pragma unroll
            for (int i = 0; i < 4; i++)
                bf[p][i] = ((const half8_t*)(Bsw + ((long long)((nblk + i) * ldb32 + kb + p)) * 512))[lane];
        __syncthreads();

#pragma unroll
        for (int kc = 0; kc < 2; kc++) {
            half8_t af[4];
#pragma unroll
            for (int i = 0; i < 4; i++)
                af[i] = *(const half8_t*)&As[kc][wy + i * 16 + l16][cra];
#pragma unroll
            for (int mi = 0; mi < 4; mi++)
#pragma unroll
                for (int ni = 0; ni < 4; ni++)
                    acc[mi][ni] = __builtin_amdgcn_mfma_f32_16x16x32_f16(af[mi], bf[kc][ni], acc[mi][ni], 0, 0, 0);
        }
    }

    float*    fC = (float*)C;
    _Float16* hC = (_Float16*)C;
#pragma unroll
    for (int mi = 0; mi < 4; mi++)
#pragma unroll
        for (int ni = 0; ni < 4; ni++)
#pragma unroll
            for (int r = 0; r < 4; r++) {
                int row = m0 + wy + mi * 16 + quad * 4 + r;
                int col = n0 + wx + ni * 16 + l16;
                float v = acc[mi][ni][r];
                if (bias) v += bias[hh * bias_h + col];
                if (out_mode <= 1) {
                    long long addr = coff + (long long)row * c_rs + (long long)col * c_cs;
                    if (out_mode) fC[addr] = v; else hC[addr] = (_Float16)v;
                } else {
                    int n = (out_mode == 2) ? row : col;
                    int k = (out_mode == 2) ? col : row;
                    long long addr = coff + ((long long)((n >> 4) * c_ld + (k >> 5))) * 512
                                   + (((k >> 3) & 3) * 16 + (n & 15)) * 8 + (k & 7);
                    hC[addr] = (_Float16)v;
                }
            }
}

// ------------- masked softmax, 8 heads per block (mask row reused via L1) -------------
__global__ __launch_bounds__(512) void softmax_mask8_kernel(_Float16* __restrict__ sc,
                                                            const int* __restrict__ mask)
{
    int b = blockIdx.z, s = blockIdx.x;
    int wave = threadIdx.x >> 6, lane = threadIdx.x & 63;
    _Float16* row = sc + ((long long)(b * H_ + wave) * S_ + s) * S_;
    const int* mrow = mask + ((long long)b * S_ + s) * S_;

    half8_t h[4];
    float v[32];
    float mx = -3.0e38f;
#pragma unroll
    for (int j = 0; j < 4; j++) {
        int c = j * 512 + lane * 8;
        h[j] = *(const half8_t*)(row + c);
        int4 mA = *(const int4*)(mrow + c);
        int4 mB = *(const int4*)(mrow + c + 4);
        int mm[8] = { mA.x, mA.y, mA.z, mA.w, mB.x, mB.y, mB.z, mB.w };
#pragma unroll
        for (int e = 0; e < 8; e++) {
            float val = mm[e] ? (float)h[j][e] : -1.0e9f;
            v[j * 8 + e] = val;
            mx = fmaxf(mx, val);
        }
    }
#pragma unroll
    for (int o = 32; o > 0; o >>= 1) mx = fmaxf(mx, __shfl_xor(mx, o));

    float sum = 0.0f;
#pragma unroll
    for (int i = 0; i < 32; i++) { v[i] = __expf(v[i] - mx); sum += v[i]; }
#pragma unroll
    for (int o = 32; o > 0; o >>= 1) sum += __shfl_xor(sum, o);

    float inv = 1.0f / sum;
#pragma unroll
    for (int j = 0; j < 4; j++) {
#pragma unroll
        for (int e = 0; e < 8; e++) h[j][e] = (_Float16)(v[j * 8 + e] * inv);
        *(half8_t*)(row + j * 512 + lane * 8) = h[j];
    }
}

// ------------- split-K GEMM 128(M)x64(N): A via LDS, B' direct; atomic fp32 ------------
__global__ __launch_bounds__(256) void gemm_splitk_kernel(
    const _Float16* __restrict__ A, const _Float16* __restrict__ Bsw,
    const float* __restrict__ bias, float* __restrict__ C,
    int K, int lda, int ldb32, int ldc, int ksplit)
{
    int m0 = blockIdx.y * 128;
    int n0 = blockIdx.x * 64;
    int kchunk = K / ksplit;
    int kbeg = blockIdx.z * kchunk;
    int kend = kbeg + kchunk;

    __shared__ __align__(16) _Float16 As[128][32];   // 8 KB

    int tid  = threadIdx.x;
    int wave = tid >> 6, lane = tid & 63;
    int quad = lane >> 4, l16 = lane & 15;
    int wy = (wave >> 1) * 64, wx = (wave & 1) * 32;

    int srow = (wave << 4) + (lane >> 2);
    int scg = ((lane & 3) ^ ((lane >> 3) & 3)) * 8;
    _Float16* lA0 = &As[0][0] + (wave << 9);
    int cra = (quad ^ ((l16 >> 1) & 3)) * 8;
    int nblk = (n0 + wx) >> 4;

    floatx4 acc[4][2] = {};

    for (int k0 = kbeg; k0 < kend; k0 += 32) {
        if (k0 != kbeg) __syncthreads();
        const _Float16* gA = A + (long long)(m0 + srow) * lda + k0 + scg;
#pragma unroll
        for (int j = 0; j < 2; j++)
            __builtin_amdgcn_global_load_lds((gas_ptr)(gA + (long long)(j << 6) * lda),
                                             (las_ptr)(lA0 + (j << 11)), 16, 0, 0);
        half8_t bf[2];
        int kb = k0 >> 5;
#pragma unroll
        for (int i = 0; i < 2; i++)
            bf[i] = ((const half8_t*)(Bsw + ((long long)((nblk + i) * ldb32 + kb)) * 512))[lane];
        __syncthreads();

        half8_t af[4];
#pragma unroll
        for (int i = 0; i < 4; i++)
            af[i] = *(const half8_t*)&As[wy + i * 16 + l16][cra];
#pragma unroll
        for (int mi = 0; mi < 4; mi++)
#pragma unroll
            for (int ni = 0; ni < 2; ni++)
                acc[mi][ni] = __builtin_amdgcn_mfma_f32_16x16x32_f16(af[mi], bf[ni], acc[mi][ni], 0, 0, 0);
    }

    int addb = (blockIdx.z == 0) && bias;
#pragma unroll
    for (int mi = 0; mi < 4; mi++)
#pragma unroll
        for (int ni = 0; ni < 2; ni++)
#pragma unroll
            for (int r = 0; r < 4; r++) {
                int row = m0 + wy + mi * 16 + quad * 4 + r;
                int col = n0 + wx + ni * 16 + l16;
                float v = acc[mi][ni][r];
                if (addb) v += bias[col];
                atomicAdd(&C[(long long)row * ldc + col], v);
            }
}

extern "C" void kernel_launch(void* const* d_in, const int* in_sizes, int n_in,
                              void* d_out, int out_size, void* d_ws, size_t ws_size,
                              hipStream_t stream)
{
    const float* qin = (const float*)d_in[0];
    const float* kin = (const float*)d_in[1];
    const float* vin = (const float*)d_in[2];
    const int*   mask = (const int*)d_in[3];
    const float* Wq = (const float*)d_in[4];
    const float* bq = (const float*)d_in[5];
    const float* Wk = (const float*)d_in[6];
    const float* bk = (const float*)d_in[7];
    const float* Wv = (const float*)d_in[8];
    const float* bv = (const float*)d_in[9];
    const float* Wo = (const float*)d_in[10];
    const float* bo = (const float*)d_in[11];
    float* out = (float*)d_out;

    char* ws = (char*)d_ws;
    size_t off = 0;
    _Float16* WoP = (_Float16*)(ws + off); off += (size_t)E_ * HE_ * 2;           // 4 MiB
    _Float16* Qb  = (_Float16*)(ws + off); off += (size_t)B_ * H_ * S_ * E_ * 2;  // 32 MiB
    _Float16* KbP = (_Float16*)(ws + off); off += (size_t)B_ * H_ * S_ * E_ * 2;  // 32 MiB
    _Float16* VTP = (_Float16*)(ws + off); off += (size_t)B_ * H_ * E_ * S_ * 2;  // 32 MiB
    size_t region = off;
    _Float16* Xq  = (_Float16*)(ws + region);
    _Float16* Xk  = Xq  + (size_t)B_ * S_ * D_;
    _Float16* Xv  = Xk  + (size_t)B_ * S_ * D_;
    _Float16* WqP = Xv  + (size_t)B_ * S_ * D_;
    _Float16* WkP = WqP + (size_t)H_ * E_ * D_;
    _Float16* WvP = WkP + (size_t)H_ * E_ * D_;
    _Float16* SC  = (_Float16*)(ws + region);   // fp16 scores -> P (overlays dead scratch)
    _Float16* cat = Qb;                          // aliases Q (dead after scores GEMM)

    long long SE = (long long)S_ * E_;
    long long SS = (long long)S_ * S_;
    long long ES = (long long)E_ * S_;
    long long SD = (long long)S_ * D_;
    long long ED = (long long)E_ * D_;

    // zero d_out (split-K atomic accumulation target)
    (void)hipMemsetAsync(d_out, 0, (size_t)out_size * sizeof(float), stream);

    // 1) cast q,k,v to fp16
    int n4 = B_ * S_ * D_ / 4;
    cast3_f16_kernel<<<dim3(n4 / 256, 3), 256, 0, stream>>>(qin, kin, vin, Xq, Xk, Xv, n4);

    // 2) pack weights into B' fragment layout
    pack3_kernel<<<dim3(E_ / 16, D_ / 128, 24), 256, 0, stream>>>(
        Wq, Wk, Wv, WqP, WkP, WvP, D_, E_);
    pack1_kernel<<<dim3(E_ / 16, HE_ / 128, 1), 256, 0, stream>>>(Wo, WoP, HE_, E_);

    // 3) projections (K=D). Q -> flat; K -> packed(n=row s, k=e); V -> packed(n=col e, k=s)
    gemm_asb_kernel<<<dim3(E_ / 128, S_ / 128, B_ * H_), 256, 0, stream>>>(
        Xq, WqP, bq, Qb, 0, D_, D_, D_ / 32,
        SD, 0, 0, ED, (long long)H_ * SE, SE, E_, 1, 0, H_, E_);
    gemm_asb_kernel<<<dim3(E_ / 128, S_ / 128, B_ * H_), 256, 0, stream>>>(
        Xk, WkP, bk, KbP, 2, D_, D_, D_ / 32,
        SD, 0, 0, ED, (long long)H_ * SE, SE, 0, 0, E_ / 32, H_, E_);
    gemm_asb_kernel<<<dim3(E_ / 128, S_ / 128, B_ * H_), 256, 0, stream>>>(
        Xv, WvP, bv, VTP, 3, D_, D_, D_ / 32,
        SD, 0, 0, ED, (long long)H_ * ES, ES, 0, 0, S_ / 32, H_, E_);

    // 4a) raw scores: A=Qb, B'=KbP -> SC flat [z][s][t]
    gemm_asb_kernel<<<dim3(S_ / 128, S_ / 128, B_ * H_), 256, 0, stream>>>(
        Qb, KbP, nullptr, SC, 0, E_, E_, E_ / 32,
        0, SE, 0, SE, 0, SS, S_, 1, 0, B_ * H_ * 2 /*bb=0,hh=z*/, 0);

    // 4b) masked softmax in place
    softmax_mask8_kernel<<<dim3(S_, 1, B_), 512, 0, stream>>>(SC, mask);

    // 4c) P @ V: A=SC, B'=VTP -> cat flat [b][s][h*E+e]
    gemm_asb_kernel<<<dim3(E_ / 128, S_ / 128, B_ * H_), 256, 0, stream>>>(
        SC, VTP, nullptr, cat, 0, S_, S_, S_ / 32,
        (long long)H_ * SS, SS, (long long)H_ * ES, ES,
        (long long)S_ * HE_, E_, HE_, 1, 0, H_, 0);

    // 5) output projection: split-K (4), A=cat, B'=WoP
    gemm_splitk_kernel<<<dim3(E_ / 64, (B_ * S_) / 128, 4), 256, 0, stream>>>(
        cat, WoP, bo, out, HE_, HE_, HE_ / 32, E_, 4);
}

// Round 10
// 486.455 us; speedup vs baseline: 1.3108x; 1.3108x over previous
//
#include <hip/hip_runtime.h>

#define B_  2
#define S_  2048
#define D_  512
#define H_  8
#define E_  512
#define HE_ 4096

typedef _Float16 half8_t  __attribute__((ext_vector_type(8)));
typedef _Float16 half4_t  __attribute__((ext_vector_type(4)));
typedef float    floatx4  __attribute__((ext_vector_type(4)));
typedef __attribute__((address_space(1))) const unsigned int* gas_ptr;
typedef __attribute__((address_space(3))) unsigned int*       las_ptr;

// ---------------- fused cast fp32 -> fp16 for q,k,v ----------------
__global__ __launch_bounds__(256) void cast3_f16_kernel(
    const float* __restrict__ s0, const float* __restrict__ s1, const float* __restrict__ s2,
    _Float16* __restrict__ d0, _Float16* __restrict__ d1, _Float16* __restrict__ d2, int n4) {
    int i = blockIdx.x * 256 + threadIdx.x;
    if (i >= n4) return;
    const float* s = (blockIdx.y == 0) ? s0 : (blockIdx.y == 1) ? s1 : s2;
    _Float16*    d = (blockIdx.y == 0) ? d0 : (blockIdx.y == 1) ? d1 : d2;
    float4 v = ((const float4*)s)[i];
    half4_t h = { (_Float16)v.x, (_Float16)v.y, (_Float16)v.z, (_Float16)v.w };
    ((half4_t*)d)[i] = h;
}

// ------------- transpose + cast: 3 sources selected by z (Wq/Wk/Wv), each [H][R][C] ------
__global__ __launch_bounds__(256) void transpose3_cast_kernel(
    const float* __restrict__ p0, const float* __restrict__ p1, const float* __restrict__ p2,
    _Float16* __restrict__ q0, _Float16* __restrict__ q1, _Float16* __restrict__ q2,
    int R, int C) {
    __shared__ float t[32][33];
    int which = blockIdx.z >> 3, hh = blockIdx.z & 7;
    const float* src = ((which == 0) ? p0 : (which == 1) ? p1 : p2) + (long long)hh * R * C;
    _Float16*    dst = ((which == 0) ? q0 : (which == 1) ? q1 : q2) + (long long)hh * R * C;
    int c0 = blockIdx.x * 32, r0 = blockIdx.y * 32;
    int tx = threadIdx.x, ty = threadIdx.y;
#pragma unroll
    for (int i = 0; i < 32; i += 8)
        t[ty + i][tx] = src[(long long)(r0 + ty + i) * C + (c0 + tx)];
    __syncthreads();
#pragma unroll
    for (int i = 0; i < 32; i += 8)
        dst[(long long)(c0 + ty + i) * R + (r0 + tx)] = (_Float16)t[tx][ty + i];
}

__global__ __launch_bounds__(256) void transpose_cast_kernel(const float* __restrict__ src,
                                                             _Float16* __restrict__ dst,
                                                             int R, int C) {
    __shared__ float t[32][33];
    int c0 = blockIdx.x * 32, r0 = blockIdx.y * 32;
    int tx = threadIdx.x, ty = threadIdx.y;
#pragma unroll
    for (int i = 0; i < 32; i += 8)
        t[ty + i][tx] = src[(long long)(r0 + ty + i) * C + (c0 + tx)];
    __syncthreads();
#pragma unroll
    for (int i = 0; i < 32; i += 8)
        dst[(long long)(c0 + ty + i) * R + (r0 + tx)] = (_Float16)t[tx][ty + i];
}

// ===== shared GEMM core notes (r6 structure + r9-validated XOR swizzle) =====
// 128x128 tile, BK=64 as two k-panels [2][128][32]; 4 waves 2x2, wave 64x64.
// Staging: wave w -> panel (w&1), rows (w>>1)*64..+64, per-lane global col
//   scg = ((lane&3) ^ ((lane>>3)&3)) * 8  (swizzled 16B chunk of the 64B row span)
// Fragment read col: cra = (quad ^ ((l16>>1)&3)) * 8 (undoes swizzle; spreads each
//   b128 read to 4 lanes per 4-bank group = LDS minimum; r9 measured 0 conflicts).

// ------------- merged QKV projection: z = which*16 + bb*8 + hh -------------
// Q,K -> flat [b,h,s,e]; V -> VT [b,h,e,s] with half4 stores down s.
__global__ __launch_bounds__(256) void gemm_qkv_kernel(
    const _Float16* __restrict__ Xq, const _Float16* __restrict__ Xk, const _Float16* __restrict__ Xv,
    const _Float16* __restrict__ WqT, const _Float16* __restrict__ WkT, const _Float16* __restrict__ WvT,
    const float* __restrict__ bq, const float* __restrict__ bk, const float* __restrict__ bv,
    _Float16* __restrict__ Qb, _Float16* __restrict__ Kb, _Float16* __restrict__ VT)
{
    int z = blockIdx.z;
    int which = z >> 4, zz = z & 15;
    int bb = zz >> 3, hh = zz & 7;
    const _Float16* A  = ((which == 0) ? Xq : (which == 1) ? Xk : Xv) + (long long)bb * S_ * D_;
    const _Float16* Bt = ((which == 0) ? WqT : (which == 1) ? WkT : WvT) + (long long)hh * E_ * D_;
    const float* bias  = ((which == 0) ? bq : (which == 1) ? bk : bv) + hh * E_;

    int m0 = blockIdx.y * 128;   // s
    int n0 = blockIdx.x * 128;   // e

    __shared__ __align__(16) _Float16 As[2][128][32];
    __shared__ __align__(16) _Float16 Bs[2][128][32];

    int tid  = threadIdx.x;
    int wave = tid >> 6, lane = tid & 63;
    int quad = lane >> 4, l16 = lane & 15;
    int wy = (wave >> 1) * 64, wx = (wave & 1) * 64;
    int pw = wave & 1, rw = (wave >> 1) * 64;
    int sr = lane >> 2;
    int scg = ((lane & 3) ^ ((lane >> 3) & 3)) * 8;
    _Float16* lA0 = &As[pw][rw][0];
    _Float16* lB0 = &Bs[pw][rw][0];
    int cra = (quad ^ ((l16 >> 1) & 3)) * 8;

    floatx4 acc[4][4] = {};

    for (int k0 = 0; k0 < D_; k0 += 64) {
        if (k0) __syncthreads();
        const _Float16* gA = A + (long long)(m0 + rw + sr) * D_ + k0 + pw * 32 + scg;
        const _Float16* gB = Bt + (long long)(n0 + rw + sr) * D_ + k0 + pw * 32 + scg;
#pragma unroll
        for (int j = 0; j < 4; j++) {
            __builtin_amdgcn_global_load_lds((gas_ptr)(gA + (long long)(j * 16) * D_),
                                             (las_ptr)(lA0 + j * 512), 16, 0, 0);
            __builtin_amdgcn_global_load_lds((gas_ptr)(gB + (long long)(j * 16) * D_),
                                             (las_ptr)(lB0 + j * 512), 16, 0, 0);
        }
        __syncthreads();
#pragma unroll
        for (int kc = 0; kc < 2; kc++) {
            half8_t af[4], bf[4];
#pragma unroll
            for (int i = 0; i < 4; i++) {
                af[i] = *(const half8_t*)&As[kc][wy + i * 16 + l16][cra];
                bf[i] = *(const half8_t*)&Bs[kc][wx + i * 16 + l16][cra];
            }
#pragma unroll
            for (int mi = 0; mi < 4; mi++)
#pragma unroll
                for (int ni = 0; ni < 4; ni++)
                    acc[mi][ni] = __builtin_amdgcn_mfma_f32_16x16x32_f16(af[mi], bf[ni], acc[mi][ni], 0, 0, 0);
        }
    }

    if (which < 2) {
        _Float16* C = ((which == 0) ? Qb : Kb) + ((long long)(bb * H_ + hh)) * S_ * E_;
#pragma unroll
        for (int mi = 0; mi < 4; mi++)
#pragma unroll
            for (int ni = 0; ni < 4; ni++)
#pragma unroll
                for (int r = 0; r < 4; r++) {
                    int row = m0 + wy + mi * 16 + quad * 4 + r;
                    int col = n0 + wx + ni * 16 + l16;
                    C[(long long)row * E_ + col] = (_Float16)(acc[mi][ni][r] + bias[col]);
                }
    } else {
        _Float16* C = VT + ((long long)(bb * H_ + hh)) * E_ * S_;
#pragma unroll
        for (int mi = 0; mi < 4; mi++)
#pragma unroll
            for (int ni = 0; ni < 4; ni++) {
                int row = m0 + wy + mi * 16 + quad * 4;     // s, multiple of 4
                int col = n0 + wx + ni * 16 + l16;          // e
                float bcol = bias[col];
                half4_t h4 = { (_Float16)(acc[mi][ni][0] + bcol), (_Float16)(acc[mi][ni][1] + bcol),
                               (_Float16)(acc[mi][ni][2] + bcol), (_Float16)(acc[mi][ni][3] + bcol) };
                *(half4_t*)(C + (long long)col * S_ + row) = h4;   // VT[e][s..s+3]
            }
    }
}

// ------------- generic bt-GEMM (scores, PV): C f16 flat -------------
__global__ __launch_bounds__(256) void gemm_bt_kernel(
    const _Float16* __restrict__ A, const _Float16* __restrict__ Bt,
    _Float16* __restrict__ C,
    int K, int lda, int ldb,
    long long a_z, long long b_z, long long c_b, long long c_h, int c_rs, int hdiv)
{
    int z = blockIdx.z;
    int bb = z / hdiv, hh = z % hdiv;
    A  += (long long)z * a_z;
    Bt += (long long)z * b_z;
    _Float16* Cz = C + bb * c_b + hh * c_h;

    int m0 = blockIdx.y * 128;
    int n0 = blockIdx.x * 128;

    __shared__ __align__(16) _Float16 As[2][128][32];
    __shared__ __align__(16) _Float16 Bs[2][128][32];

    int tid  = threadIdx.x;
    int wave = tid >> 6, lane = tid & 63;
    int quad = lane >> 4, l16 = lane & 15;
    int wy = (wave >> 1) * 64, wx = (wave & 1) * 64;
    int pw = wave & 1, rw = (wave >> 1) * 64;
    int sr = lane >> 2;
    int scg = ((lane & 3) ^ ((lane >> 3) & 3)) * 8;
    _Float16* lA0 = &As[pw][rw][0];
    _Float16* lB0 = &Bs[pw][rw][0];
    int cra = (quad ^ ((l16 >> 1) & 3)) * 8;

    floatx4 acc[4][4] = {};

    for (int k0 = 0; k0 < K; k0 += 64) {
        if (k0) __syncthreads();
        const _Float16* gA = A + (long long)(m0 + rw + sr) * lda + k0 + pw * 32 + scg;
        const _Float16* gB = Bt + (long long)(n0 + rw + sr) * ldb + k0 + pw * 32 + scg;
#pragma unroll
        for (int j = 0; j < 4; j++) {
            __builtin_amdgcn_global_load_lds((gas_ptr)(gA + (long long)(j * 16) * lda),
                                             (las_ptr)(lA0 + j * 512), 16, 0, 0);
            __builtin_amdgcn_global_load_lds((gas_ptr)(gB + (long long)(j * 16) * ldb),
                                             (las_ptr)(lB0 + j * 512), 16, 0, 0);
        }
        __syncthreads();
#pragma unroll
        for (int kc = 0; kc < 2; kc++) {
            half8_t af[4], bf[4];
#pragma unroll
            for (int i = 0; i < 4; i++) {
                af[i] = *(const half8_t*)&As[kc][wy + i * 16 + l16][cra];
                bf[i] = *(const half8_t*)&Bs[kc][wx + i * 16 + l16][cra];
            }
#pragma unroll
            for (int mi = 0; mi < 4; mi++)
#pragma unroll
                for (int ni = 0; ni < 4; ni++)
                    acc[mi][ni] = __builtin_amdgcn_mfma_f32_16x16x32_f16(af[mi], bf[ni], acc[mi][ni], 0, 0, 0);
        }
    }

#pragma unroll
    for (int mi = 0; mi < 4; mi++)
#pragma unroll
        for (int ni = 0; ni < 4; ni++)
#pragma unroll
            for (int r = 0; r < 4; r++) {
                int row = m0 + wy + mi * 16 + quad * 4 + r;
                int col = n0 + wx + ni * 16 + l16;
                Cz[(long long)row * c_rs + col] = (_Float16)acc[mi][ni][r];
            }
}

// ------------- masked softmax, 8 heads per block (mask row reused via L1) -------------
__global__ __launch_bounds__(512) void softmax_mask8_kernel(_Float16* __restrict__ sc,
                                                            const int* __restrict__ mask)
{
    int b = blockIdx.z, s = blockIdx.x;
    int wave = threadIdx.x >> 6, lane = threadIdx.x & 63;
    _Float16* row = sc + ((long long)(b * H_ + wave) * S_ + s) * S_;
    const int* mrow = mask + ((long long)b * S_ + s) * S_;

    half8_t h[4];
    float v[32];
    float mx = -3.0e38f;
#pragma unroll
    for (int j = 0; j < 4; j++) {
        int c = j * 512 + lane * 8;
        h[j] = *(const half8_t*)(row + c);
        int4 mA = *(const int4*)(mrow + c);
        int4 mB = *(const int4*)(mrow + c + 4);
        int mm[8] = { mA.x, mA.y, mA.z, mA.w, mB.x, mB.y, mB.z, mB.w };
#pragma unroll
        for (int e = 0; e < 8; e++) {
            float val = mm[e] ? (float)h[j][e] : -1.0e9f;
            v[j * 8 + e] = val;
            mx = fmaxf(mx, val);
        }
    }
#pragma unroll
    for (int o = 32; o > 0; o >>= 1) mx = fmaxf(mx, __shfl_xor(mx, o));

    float sum = 0.0f;
#pragma unroll
    for (int i = 0; i < 32; i++) { v[i] = __expf(v[i] - mx); sum += v[i]; }
#pragma unroll
    for (int o = 32; o > 0; o >>= 1) sum += __shfl_xor(sum, o);

    float inv = 1.0f / sum;
#pragma unroll
    for (int j = 0; j < 4; j++) {
#pragma unroll
        for (int e = 0; e < 8; e++) h[j][e] = (_Float16)(v[j * 8 + e] * inv);
        *(half8_t*)(row + j * 512 + lane * 8) = h[j];
    }
}

// ------------- split-K bt-GEMM, 128(M)x64(N) tile, swizzled, fp32 atomic accumulate ------
__global__ __launch_bounds__(256) void gemm_bt_n64_splitk_kernel(
    const _Float16* __restrict__ A, const _Float16* __restrict__ Bt,
    const float* __restrict__ bias, float* __restrict__ C,
    int K, int lda, int ldb, int ldc, int ksplit)
{
    int m0 = blockIdx.y * 128;
    int n0 = blockIdx.x * 64;
    int kchunk = K / ksplit;
    int kbeg = blockIdx.z * kchunk;
    int kend = kbeg + kchunk;

    __shared__ __align__(16) _Float16 As[128][32];
    __shared__ __align__(16) _Float16 Bs[64][32];

    int tid  = threadIdx.x;
    int wave = tid >> 6, lane = tid & 63;
    int quad = lane >> 4, l16 = lane & 15;
    int wy = (wave >> 1) * 64, wx = (wave & 1) * 32;

    int srow = (wave << 4) + (lane >> 2);
    int scg = ((lane & 3) ^ ((lane >> 3) & 3)) * 8;
    _Float16* lA0 = &As[0][0] + (wave << 9);
    _Float16* lB0 = &Bs[0][0] + (wave << 9);
    int cra = (quad ^ ((l16 >> 1) & 3)) * 8;

    floatx4 acc[4][2] = {};

    for (int k0 = kbeg; k0 < kend; k0 += 32) {
        if (k0 != kbeg) __syncthreads();
        const _Float16* gA = A + (long long)(m0 + srow) * lda + k0 + scg;
        const _Float16* gB = Bt + (long long)(n0 + srow) * ldb + k0 + scg;
#pragma unroll
        for (int j = 0; j < 2; j++)
            __builtin_amdgcn_global_load_lds((gas_ptr)(gA + (long long)(j << 6) * lda),
                                             (las_ptr)(lA0 + (j << 11)), 16, 0, 0);
        __builtin_amdgcn_global_load_lds((gas_ptr)gB, (las_ptr)lB0, 16, 0, 0);
        __syncthreads();

        half8_t af[4], bf[2];
#pragma unroll
        for (int i = 0; i < 4; i++)
            af[i] = *(const half8_t*)&As[wy + i * 16 + l16][cra];
#pragma unroll
        for (int i = 0; i < 2; i++)
            bf[i] = *(const half8_t*)&Bs[wx + i * 16 + l16][cra];
#pragma unroll
        for (int mi = 0; mi < 4; mi++)
#pragma unroll
            for (int ni = 0; ni < 2; ni++)
                acc[mi][ni] = __builtin_amdgcn_mfma_f32_16x16x32_f16(af[mi], bf[ni], acc[mi][ni], 0, 0, 0);
    }

    int addb = (blockIdx.z == 0) && bias;
#pragma unroll
    for (int mi = 0; mi < 4; mi++)
#pragma unroll
        for (int ni = 0; ni < 2; ni++)
#pragma unroll
            for (int r = 0; r < 4; r++) {
                int row = m0 + wy + mi * 16 + quad * 4 + r;
                int col = n0 + wx + ni * 16 + l16;
                float v = acc[mi][ni][r];
                if (addb) v += bias[col];
                atomicAdd(&C[(long long)row * ldc + col], v);
            }
}

extern "C" void kernel_launch(void* const* d_in, const int* in_sizes, int n_in,
                              void* d_out, int out_size, void* d_ws, size_t ws_size,
                              hipStream_t stream)
{
    const float* qin = (const float*)d_in[0];
    const float* kin = (const float*)d_in[1];
    const float* vin = (const float*)d_in[2];
    const int*   mask = (const int*)d_in[3];
    const float* Wq = (const float*)d_in[4];
    const float* bq = (const float*)d_in[5];
    const float* Wk = (const float*)d_in[6];
    const float* bk = (const float*)d_in[7];
    const float* Wv = (const float*)d_in[8];
    const float* bv = (const float*)d_in[9];
    const float* Wo = (const float*)d_in[10];
    const float* bo = (const float*)d_in[11];
    float* out = (float*)d_out;

    char* ws = (char*)d_ws;
    size_t off = 0;
    _Float16* WoT = (_Float16*)(ws + off); off += (size_t)E_ * HE_ * 2;           // 4 MiB
    _Float16* Qb  = (_Float16*)(ws + off); off += (size_t)B_ * H_ * S_ * E_ * 2;  // 32 MiB
    _Float16* Kb  = (_Float16*)(ws + off); off += (size_t)B_ * H_ * S_ * E_ * 2;  // 32 MiB
    _Float16* VT  = (_Float16*)(ws + off); off += (size_t)B_ * H_ * E_ * S_ * 2;  // 32 MiB
    size_t region = off;
    _Float16* Xq  = (_Float16*)(ws + region);
    _Float16* Xk  = Xq  + (size_t)B_ * S_ * D_;
    _Float16* Xv  = Xk  + (size_t)B_ * S_ * D_;
    _Float16* WqT = Xv  + (size_t)B_ * S_ * D_;
    _Float16* WkT = WqT + (size_t)H_ * E_ * D_;
    _Float16* WvT = WkT + (size_t)H_ * E_ * D_;
    _Float16* SC  = (_Float16*)(ws + region);   // fp16 scores -> P (overlays dead scratch)
    _Float16* cat = Qb;                          // aliases Q (dead after scores GEMM)

    long long SE = (long long)S_ * E_;
    long long SS = (long long)S_ * S_;
    long long ES = (long long)E_ * S_;

    // zero d_out (split-K atomic accumulation target)
    (void)hipMemsetAsync(d_out, 0, (size_t)out_size * sizeof(float), stream);

    // 1) cast q,k,v to fp16
    int n4 = B_ * S_ * D_ / 4;
    cast3_f16_kernel<<<dim3(n4 / 256, 3), 256, 0, stream>>>(qin, kin, vin, Xq, Xk, Xv, n4);

    // 2) transpose+cast weights to Bt form
    dim3 tb(32, 8);
    transpose3_cast_kernel<<<dim3(E_ / 32, D_ / 32, 24), tb, 0, stream>>>(
        Wq, Wk, Wv, WqT, WkT, WvT, D_, E_);
    transpose_cast_kernel<<<dim3(E_ / 32, HE_ / 32, 1), tb, 0, stream>>>(Wo, WoT, HE_, E_);

    // 3) merged QKV projections: one dispatch, 48 z-slices
    gemm_qkv_kernel<<<dim3(E_ / 128, S_ / 128, 48), 256, 0, stream>>>(
        Xq, Xk, Xv, WqT, WkT, WvT, bq, bk, bv, Qb, Kb, VT);

    // 4a) raw scores [z][s][t]
    gemm_bt_kernel<<<dim3(S_ / 128, S_ / 128, B_ * H_), 256, 0, stream>>>(
        Qb, Kb, SC, E_, E_, E_, SE, SE, 0, SS, S_, 32 /*hdiv>z: bb=0,hh=z*/);

    // 4b) masked softmax in place, 8 heads per block
    softmax_mask8_kernel<<<dim3(S_, 1, B_), 512, 0, stream>>>(SC, mask);

    // 4c) P @ V -> cat[b][s][h*E+e]
    gemm_bt_kernel<<<dim3(E_ / 128, S_ / 128, B_ * H_), 256, 0, stream>>>(
        SC, VT, cat, S_, S_, S_, SS, ES, (long long)S_ * HE_, E_, HE_, H_);

    // 5) output projection: split-K (4) swizzled, atomic fp32 accumulate
    gemm_bt_n64_splitk_kernel<<<dim3(E_ / 64, (B_ * S_) / 128, 4), 256, 0, stream>>>(
        cat, WoT, bo, out, HE_, HE_, HE_, E_, 4);
}